// Round 8
// baseline (498.572 us; speedup 1.0000x reference)
//
#include <hip/hip_runtime.h>
#include <hip/hip_bf16.h>
#include <math.h>

// D=4096 K=512 HOP=512 WIN=16384 DX=25 B=128 K2=128 DY=128 K3=256 Y=193 M=128
// ws layout (bytes): same as round 6/7
//   zxb @0 (3.28MB) | h2b @3,276,800 (12.64MB) | w1b @15,921,152 (32KB)
//   w2f @15,953,920 (1.64MB) | bb @17,592,320 (12.65MB)
//   xh @30,240,768 (4.19MB) | fB @34,435,072 (8.39MB) | part @30,240,768 (aliases)

typedef __attribute__((ext_vector_type(8))) short s8v;       // 8 bf16
typedef __attribute__((ext_vector_type(8))) _Float16 half8;  // 8 fp16
typedef __attribute__((ext_vector_type(16))) float f16v;     // 32x32 acc

__device__ inline ushort f2bf(float f) {
    union { float f; unsigned u; } v; v.f = f;
    unsigned u = v.u;
    return (ushort)((u + 0x7FFFu + ((u >> 16) & 1u)) >> 16);
}

// ---------------- K0x: x -> fp16 ----------------
__global__ void k0x_xh(const float* __restrict__ x, _Float16* __restrict__ xh) {
    int i = blockIdx.x * 256 + threadIdx.x;
    xh[i] = (_Float16)x[i];
}

// ---------------- K0f: filt (4096x1024) -> fp16 tiled [k/8][n][8] ----------------
__global__ __launch_bounds__(256)
void k0f_fB(const float* __restrict__ filt, _Float16* __restrict__ fB) {
    __shared__ float tile[8][257];
    const int t   = threadIdx.x;
    const int n0  = blockIdx.x * 256;
    const int kc8 = blockIdx.y;
    for (int idx = t; idx < 8 * 256; idx += 256) {
        int kk = idx >> 8, n = idx & 255;
        tile[kk][n] = filt[(kc8 * 8 + kk) * 1024 + n0 + n];
    }
    __syncthreads();
    half8 v;
#pragma unroll
    for (int j = 0; j < 8; j++) v[j] = (_Float16)tile[j][t];
    *(half8*)(fB + (size_t)kc8 * 8192 + (size_t)(n0 + t) * 8) = v;
}

// ---------------- K0a: w1 -> bf16 [k2][dy] ----------------
__global__ void k0a_w1b(const float* __restrict__ w1, ushort* __restrict__ w1b) {
    int i = blockIdx.x * 256 + threadIdx.x;
    w1b[i] = f2bf(w1[i]);
}

// ---------------- K0b: w2 -> bf16 frag-tiled [dx][ks][q][k3][j], k2=16ks+8q+j ----------------
__global__ void k0b_w2f(const float* __restrict__ w2, ushort* __restrict__ w2f) {
    int i = blockIdx.x * 256 + threadIdx.x;   // 0..819199
    int j  = i & 7;
    int k3 = (i >> 3) & 255;
    int q  = (i >> 11) & 1;
    int ks = (i >> 12) & 7;
    int dx = i >> 15;
    int k2 = 16 * ks + 8 * q + j;
    w2f[i] = f2bf(w2[(k3 * 128 + k2) * 25 + dx]);
}

// ---------------- K0c: beta -> bf16 ----------------
__global__ void k0c_bb(const float* __restrict__ beta, ushort* __restrict__ bb) {
    int i = blockIdx.x * 256 + threadIdx.x;
    bb[i] = f2bf(beta[i]);
}

// ---------------- K1 v2: spec GEMM, tile 128x64, grid 400, 1 barrier/iter ----------------
__global__ __launch_bounds__(256)
void k1_mfma(const _Float16* __restrict__ xh, const _Float16* __restrict__ fB,
             ushort* __restrict__ zxb) {
    __shared__ _Float16 Al[2 * 4096];
    const int t  = threadIdx.x;
    const int n0 = blockIdx.x * 64;
    const int m0 = blockIdx.y * 128;
    const int w  = t >> 6, l = t & 63;
    const int wm = 32 * w;
    const int qf = l >> 5;
    const int ml = l & 31;

    const int srow = t >> 1;
    const int sq   = t & 1;
    const int gm   = m0 + srow;
    const _Float16* apt = xh + (gm / 25) * 16384 + (gm % 25) * 512 + sq * 8;
    half8* Als8 = (half8*)Al;

    const _Float16* pB = fB + (size_t)qf * 8192 + (size_t)(n0 + ml) * 8;

    f16v acc[2];
#pragma unroll
    for (int nt = 0; nt < 2; nt++)
#pragma unroll
        for (int r = 0; r < 16; r++) acc[nt][r] = 0.f;

    half8 v0 = *(const half8*)(apt);
    half8 v1 = *(const half8*)(apt + 16);

    for (int kb = 0; kb < 128; kb++) {
        const int p = kb & 1;
        Als8[p * 512 + t]       = v0;
        Als8[p * 512 + 256 + t] = v1;
        __syncthreads();
        if (kb < 127) {
            v0 = *(const half8*)(apt + (kb + 1) * 32);
            v1 = *(const half8*)(apt + (kb + 1) * 32 + 16);
        }
#pragma unroll
        for (int s = 0; s < 2; s++) {
            half8 a0 = *(const half8*)((const char*)Al + p * 8192 + s * 4096 + (wm + ml) * 32 + qf * 16);
            const _Float16* pBk = pB + ((size_t)kb * 2 + s) * 16384;
            half8 b0 = *(const half8*)(pBk);
            half8 b1 = *(const half8*)(pBk + 256);
            acc[0] = __builtin_amdgcn_mfma_f32_32x32x16_f16(a0, b0, acc[0], 0, 0, 0);
            acc[1] = __builtin_amdgcn_mfma_f32_32x32x16_f16(a0, b1, acc[1], 0, 0, 0);
        }
    }

#pragma unroll
    for (int nt = 0; nt < 2; nt++) {
#pragma unroll
        for (int r = 0; r < 16; r++) {
            float val = acc[nt][r];
            float oth = __shfl_xor(val, 1, 64);
            if (!(l & 1)) {
                float pw = fmaf(val, val, fmaf(oth, oth, 1e-14f));
                int m = m0 + wm + 4 * qf + (r & 3) + 8 * (r >> 2);
                int n = n0 + nt * 32 + ml;
                zxb[m * 512 + (n >> 1)] = f2bf(logf(pw));
            }
        }
    }
}

// ---------------- K2 v6: barrier-free fused conv1+conv2 (k2-split conv2) ----------------
// grid (7 yt, 128 b, 2 g=k3-half), 256 thr = 4 waves (u = k2-quarter).
// Wave u: conv1 for k2 [32u,32u+32) (h1 in regs), in-register C/D->B transform via
// shfl_xor(32), conv2 K-partial for k3 [128g,128g+128). NO barriers in dx loop.
// Epilogue: 2-barrier LDS tree reduction over the 4 k2-partials.
__global__ __launch_bounds__(256, 2)
void k2_mfma(const ushort* __restrict__ zxb, const ushort* __restrict__ w1b,
             const ushort* __restrict__ w2f, ushort* __restrict__ h2b) {
    __shared__ float red[2 * 4 * 64 * 17];   // 2 regions x 4352 dwords = 34,816 B
    const int t  = threadIdx.x;
    const int yt = blockIdx.x;      // 0..6
    const int b  = blockIdx.y;
    const int g  = blockIdx.z;      // k3-half
    const int y0 = yt * 32;
    const int u  = t >> 6;          // k2-quarter
    const int l  = t & 63;
    const int ml = l & 31;
    const int q  = l >> 5;
    const int y  = y0 + ml;         // 0..223 (y>192 garbage, discarded)

    // persistent conv1 A-frags: k2-tile [32u, 32u+32)
    s8v w1f[8];
    {
        const ushort* wp = w1b + (32 * u + ml) * 128 + 8 * q;
#pragma unroll
        for (int ks = 0; ks < 8; ks++)
            w1f[ks] = *(const s8v*)(wp + 16 * ks);
    }

    const ushort* zb = zxb + (size_t)b * 12800 + 2 * y + 8 * q;
    // conv2 A-frag: w2f[((dx*8 + 2u+s)*2 + q)*2048 + (128g + 32mt + ml)*8]
    const ushort* wa = w2f + (size_t)q * 2048 + (size_t)(128 * g + ml) * 8;

    f16v acc[4];
#pragma unroll
    for (int mt = 0; mt < 4; mt++)
#pragma unroll
        for (int r = 0; r < 16; r++) acc[mt][r] = 0.f;

#pragma unroll 5
    for (int dx = 0; dx < 25; dx++) {
        // ---- conv1: k2-quarter x y32, B direct from global ----
        const ushort* zp = zb + dx * 512;
        f16v c1;
#pragma unroll
        for (int r = 0; r < 16; r++) c1[r] = 0.f;
#pragma unroll
        for (int ks = 0; ks < 8; ks++) {
            s8v bf = *(const s8v*)(zp + 16 * ks);
            c1 = __builtin_amdgcn_mfma_f32_32x32x16_bf16(w1f[ks], bf, c1, 0, 0, 0);
        }
        // ---- relu + pack row-quads: pk[2*g4+..] rows 8*g4+4q+{0..3} ----
        unsigned pk[8];
#pragma unroll
        for (int g4 = 0; g4 < 4; g4++) {
            pk[2 * g4 + 0] = (unsigned)f2bf(fmaxf(c1[4 * g4 + 0], 0.f))
                           | ((unsigned)f2bf(fmaxf(c1[4 * g4 + 1], 0.f)) << 16);
            pk[2 * g4 + 1] = (unsigned)f2bf(fmaxf(c1[4 * g4 + 2], 0.f))
                           | ((unsigned)f2bf(fmaxf(c1[4 * g4 + 3], 0.f)) << 16);
        }
        // ---- in-register C/D -> B-operand transform (shfl_xor lane^32) ----
        s8v hf[2];
#pragma unroll
        for (int s = 0; s < 2; s++) {
            int gk = 2 * s + q;          // keep group
            int gs = 2 * s + 1 - q;      // send group
            unsigned k0 = pk[2 * gk + 0], k1 = pk[2 * gk + 1];
            unsigned r0 = (unsigned)__shfl_xor((int)pk[2 * gs + 0], 32, 64);
            unsigned r1 = (unsigned)__shfl_xor((int)pk[2 * gs + 1], 32, 64);
            union { unsigned d[4]; s8v v; } fb;
            fb.d[0] = q ? r0 : k0;   // Q1: rows 16s+8q+0..3
            fb.d[1] = q ? r1 : k1;
            fb.d[2] = q ? k0 : r0;   // Q2: rows 16s+8q+4..7
            fb.d[3] = q ? k1 : r1;
            hf[s] = fb.v;
        }
        // ---- conv2: K-partial (this wave's k2 32) for k3-half 128 ----
#pragma unroll
        for (int s = 0; s < 2; s++) {
            const ushort* ap = wa + (size_t)(dx * 8 + 2 * u + s) * 4096;
#pragma unroll
            for (int mt = 0; mt < 4; mt++) {
                s8v af = *(const s8v*)(ap + mt * 256);
                acc[mt] = __builtin_amdgcn_mfma_f32_32x32x16_bf16(af, hf[s], acc[mt], 0, 0, 0);
            }
        }
    }

    // ---- epilogue: tree-reduce 4 k2-partials via LDS (2 barriers) ----
    // region R: red[R*4352 + (mt*64 + l)*17 + r]
    if (u >= 2) {
        float* dst = red + (u - 2) * 4352 + l * 17;
#pragma unroll
        for (int mt = 0; mt < 4; mt++)
#pragma unroll
            for (int r = 0; r < 16; r++)
                dst[mt * 64 * 17 + r] = acc[mt][r];
    }
    __syncthreads();
    if (u < 2) {
        const float* src = red + u * 4352 + l * 17;
#pragma unroll
        for (int mt = 0; mt < 4; mt++)
#pragma unroll
            for (int r = 0; r < 16; r++)
                acc[mt][r] += src[mt * 64 * 17 + r];
    }
    if (u == 1) {
        float* dst = red + 4352 + l * 17;
#pragma unroll
        for (int mt = 0; mt < 4; mt++)
#pragma unroll
            for (int r = 0; r < 16; r++)
                dst[mt * 64 * 17 + r] = acc[mt][r];
    }
    __syncthreads();
    if (u == 0 && y < 193) {
        const float* src = red + 4352 + l * 17;
#pragma unroll
        for (int mt = 0; mt < 4; mt++) {
#pragma unroll
            for (int r = 0; r < 16; r++) {
                float v = acc[mt][r] + src[mt * 64 * 17 + r];
                int k3 = 128 * g + 32 * mt + 4 * q + (r & 3) + 8 * (r >> 2);
                h2b[((size_t)b * 256 + k3) * 193 + y] = f2bf(fmaxf(v, 0.f));
            }
        }
    }
}

// ---------------- K4: y partials via bf16 MFMA, 193-way k-split ----------------
__global__ __launch_bounds__(256)
void k4_mfma(const ushort* __restrict__ h2b, const ushort* __restrict__ bb,
             float* __restrict__ part) {
    const int t = threadIdx.x, w = t >> 6, l = t & 63;
    const int s = blockIdx.x;
    const int kb = s * 256;
    const int qf = l >> 5;
    const int ml = l & 31;
    const ushort* pa  = h2b + (size_t)(w * 32 + ml) * 49408 + kb + qf * 8;
    const ushort* pb0 = bb  + (size_t)ml * 49408 + kb + qf * 8;

    f16v acc[4];
#pragma unroll
    for (int nt = 0; nt < 4; nt++)
#pragma unroll
        for (int r = 0; r < 16; r++) acc[nt][r] = 0.f;

    for (int ks = 0; ks < 16; ks++) {
        s8v af = *(const s8v*)(pa + ks * 16);
#pragma unroll
        for (int nt = 0; nt < 4; nt++) {
            s8v bf = *(const s8v*)(pb0 + (size_t)nt * 32 * 49408 + ks * 16);
            acc[nt] = __builtin_amdgcn_mfma_f32_32x32x16_bf16(af, bf, acc[nt], 0, 0, 0);
        }
    }
    float* pp = part + (size_t)s * 16384;
#pragma unroll
    for (int nt = 0; nt < 4; nt++)
#pragma unroll
        for (int r = 0; r < 16; r++) {
            int m = w * 32 + 4 * qf + (r & 3) + 8 * (r >> 2);
            pp[m * 128 + nt * 32 + ml] = acc[nt][r];
        }
}

// ---------------- K5: reduce 193 partials ----------------
__global__ void k5_red(const float* __restrict__ part, float* __restrict__ out) {
    int i = blockIdx.x * 256 + threadIdx.x;
    float s = 0.f;
    for (int k = 0; k < 193; k++) s += part[(size_t)k * 16384 + i];
    out[i] = s;
}

extern "C" void kernel_launch(void* const* d_in, const int* in_sizes, int n_in,
                              void* d_out, int out_size, void* d_ws, size_t ws_size,
                              hipStream_t stream) {
    const float* x    = (const float*)d_in[0];
    const float* filt = (const float*)d_in[1];
    const float* w1   = (const float*)d_in[2];
    const float* w2   = (const float*)d_in[3];
    const float* beta = (const float*)d_in[4];
    float* out = (float*)d_out;

    char* ws = (char*)d_ws;
    ushort*   zxb  = (ushort*)(ws + 0);
    ushort*   h2b  = (ushort*)(ws + 3276800);
    ushort*   w1b  = (ushort*)(ws + 15921152);
    ushort*   w2f  = (ushort*)(ws + 15953920);
    ushort*   bb   = (ushort*)(ws + 17592320);
    _Float16* xh   = (_Float16*)(ws + 30240768);
    _Float16* fB   = (_Float16*)(ws + 34435072);
    float*    part = (float*)(ws + 30240768);

    k0x_xh<<<8192, 256, 0, stream>>>(x, xh);
    k0f_fB<<<dim3(4, 512), 256, 0, stream>>>(filt, fB);
    k0a_w1b<<<64, 256, 0, stream>>>(w1, w1b);
    k0b_w2f<<<3200, 256, 0, stream>>>(w2, w2f);
    k0c_bb<<<24704, 256, 0, stream>>>(beta, bb);
    k1_mfma<<<dim3(16, 25), 256, 0, stream>>>(xh, fB, zxb);
    k2_mfma<<<dim3(7, 128, 2), 256, 0, stream>>>(zxb, w1b, w2f, h2b);
    k4_mfma<<<193, 256, 0, stream>>>(h2b, bb, part);
    k5_red<<<64, 256, 0, stream>>>(part, out);
}